// Round 3
// baseline (175.368 us; speedup 1.0000x reference)
//
#include <hip/hip_runtime.h>
#include <hip/hip_cooperative_groups.h>
#include <hip/hip_bf16.h>

namespace cg = cooperative_groups;

#define NB   128
#define NT   256
#define C0   8192
#define C1   2048
#define CE0  131072
#define CE1  32768
#define CE2  2048

struct KP {
  const float* x; const int* ei;
  const float* W0; const float* a1_0; const float* a2_0; const float* b0; const float* Wr0;
  const float* Wf; const float* a1f; const float* a2f; const float* bf;
  const float* Wfc; const float* bfc;
  float* out;
  int N, E, t;
  int* cnt;     // [0]=ne0 [1]=ne1 [2]=ne2 [3]=n0 [4]=n1
  float* wa;    // wa1[0..6], wa2[8..14]
  int* idx0; int* idx1; int* list0; int* list1;
  float* s0; float* acc0; float* s1; float* acc1;
  int* e0s; int* e0d; int* e1s; int* e1d; int* e2s;
  float* f0; float* hh0; float* av10; float* av20;
  float* f1; float* hh1; float* av11; float* av21;
};

__device__ __forceinline__ float lrelu(float v, float a){ return v >= 0.f ? v : a*v; }
__device__ __forceinline__ float selu_f(float v){
  const float sc = 1.0507009873554805f, al = 1.6732632423543772f;
  return v > 0.f ? sc*v : sc*al*expm1f(v);
}
// claim node into compact set; zero its denom + 128-wide accumulator slot
__device__ __forceinline__ void claim(int* idx, int* list, int* cnt, int cap, int node,
                                      float* s, float* acc){
  if (atomicCAS(&idx[node], -1, -2) == -1){
    int slot = atomicAdd(cnt, 1);
    if (slot < cap){
      list[slot] = node;
      s[slot] = 0.f;
      float* a = acc + (size_t)slot * 128;
      #pragma unroll 4
      for (int k = 0; k < 128; ++k) a[k] = 0.f;
      idx[node] = slot;
    }
  }
}

__global__ void __launch_bounds__(NT) fused(KP p){
  cg::grid_group grid = cg::this_grid();
  __shared__ int   bm[2048];     // node-membership bitmap (N<=65536)
  __shared__ float sf[128];
  __shared__ float red[128];
  const int tid = threadIdx.x, bid = blockIdx.x;
  const int gtid = bid*NT + tid, gsz = gridDim.x*NT;
  const int t = p.t, E = p.E, N = p.N;
  const int bmw = (N + 31) >> 5;

  // ---- P0: init idx maps, counters, wa precompute, slot-0 (node t) ----
  for (int u = gtid; u < N; u += gsz){
    int v = (u == t) ? 0 : -1;
    p.idx0[u] = v; p.idx1[u] = v;
  }
  if (bid == 0){
    if (tid < 7){
      float sA = 0.f, sB = 0.f;
      for (int k = 0; k < 128; ++k){ float wv = p.W0[tid*128+k]; sA += wv*p.a1_0[k]; sB += wv*p.a2_0[k]; }
      p.wa[tid] = sA; p.wa[8+tid] = sB;
    }
    if (tid < 128){ p.acc0[tid] = 0.f; p.acc1[tid] = 0.f; }
    else if (tid == 128){
      p.s0[0] = 0.f; p.s1[0] = 0.f; p.list0[0] = t; p.list1[0] = t;
      p.cnt[0] = 0; p.cnt[1] = 0; p.cnt[2] = 0; p.cnt[3] = 1; p.cnt[4] = 1;
    }
  }
  grid.sync();

  // ---- P1: scan edges into t -> e2 list, claim S1 (and S0) ----
  {
    const int4* d4 = (const int4*)(p.ei + E);
    const int nv = E >> 2;
    for (int i = gtid; i < nv; i += gsz){
      int4 d = d4[i];
      if (d.x==t || d.y==t || d.z==t || d.w==t){
        #pragma unroll
        for (int m = 0; m < 4; ++m){
          int dd = (&d.x)[m];
          if (dd == t){
            int s = p.ei[4*i + m];
            int slot = atomicAdd(&p.cnt[2], 1);
            if (slot < CE2) p.e2s[slot] = s;
            claim(p.idx1, p.list1, &p.cnt[4], C1, s, p.s1, p.acc1);
            claim(p.idx0, p.list0, &p.cnt[3], C0, s, p.s0, p.acc0);
          }
        }
      }
    }
    for (int i = (nv<<2) + gtid; i < E; i += gsz){
      int dd = p.ei[E + i];
      if (dd == t){
        int s = p.ei[i];
        int slot = atomicAdd(&p.cnt[2], 1);
        if (slot < CE2) p.e2s[slot] = s;
        claim(p.idx1, p.list1, &p.cnt[4], C1, s, p.s1, p.acc1);
        claim(p.idx0, p.list0, &p.cnt[3], C0, s, p.s0, p.acc0);
      }
    }
  }
  grid.sync();

  // ---- P2: scan edges into S1 -> e1 list, claim srcs into S0 ----
  {
    for (int i = tid; i < bmw; i += NT) bm[i] = 0;
    __syncthreads();
    int n1 = min(p.cnt[4], C1);
    for (int i = tid; i < n1; i += NT){ int u = p.list1[i]; atomicOr(&bm[u>>5], 1 << (u&31)); }
    __syncthreads();
    const int4* d4 = (const int4*)(p.ei + E);
    const int nv = E >> 2;
    for (int i = gtid; i < nv; i += gsz){
      int4 d = d4[i];
      #pragma unroll
      for (int m = 0; m < 4; ++m){
        int dd = (&d.x)[m];
        if ((bm[dd>>5] >> (dd&31)) & 1){
          int s = p.ei[4*i + m];
          int slot = atomicAdd(&p.cnt[1], 1);
          if (slot < CE1){ p.e1s[slot] = s; p.e1d[slot] = dd; }
          claim(p.idx0, p.list0, &p.cnt[3], C0, s, p.s0, p.acc0);
        }
      }
    }
    for (int i = (nv<<2) + gtid; i < E; i += gsz){
      int dd = p.ei[E + i];
      if ((bm[dd>>5] >> (dd&31)) & 1){
        int s = p.ei[i];
        int slot = atomicAdd(&p.cnt[1], 1);
        if (slot < CE1){ p.e1s[slot] = s; p.e1d[slot] = dd; }
        claim(p.idx0, p.list0, &p.cnt[3], C0, s, p.s0, p.acc0);
      }
    }
  }
  grid.sync();

  // ---- P3: scan edges into S0 -> e0 list ----
  {
    for (int i = tid; i < bmw; i += NT) bm[i] = 0;
    __syncthreads();
    int n0 = min(p.cnt[3], C0);
    for (int i = tid; i < n0; i += NT){ int u = p.list0[i]; atomicOr(&bm[u>>5], 1 << (u&31)); }
    __syncthreads();
    const int4* d4 = (const int4*)(p.ei + E);
    const int nv = E >> 2;
    for (int i = gtid; i < nv; i += gsz){
      int4 d = d4[i];
      #pragma unroll
      for (int m = 0; m < 4; ++m){
        int dd = (&d.x)[m];
        if ((bm[dd>>5] >> (dd&31)) & 1){
          int slot = atomicAdd(&p.cnt[0], 1);
          if (slot < CE0){ p.e0s[slot] = p.ei[4*i + m]; p.e0d[slot] = dd; }
        }
      }
    }
    for (int i = (nv<<2) + gtid; i < E; i += gsz){
      int dd = p.ei[E + i];
      if ((bm[dd>>5] >> (dd&31)) & 1){
        int slot = atomicAdd(&p.cnt[0], 1);
        if (slot < CE0){ p.e0s[slot] = p.ei[i]; p.e0d[slot] = dd; }
      }
    }
  }
  grid.sync();

  // ---- P4: level-0 edge accumulation (unnormalized) ----
  {
    int ne0 = min(p.cnt[0], CE0);
    for (int i = bid; i < ne0; i += gridDim.x){
      int s = p.e0s[i], d = p.e0d[i];
      float f = 0.f;
      #pragma unroll
      for (int j = 0; j < 7; ++j) f += p.x[s*7+j]*p.wa[j] + p.x[d*7+j]*p.wa[8+j];
      float e = expf(lrelu(f, 0.2f));
      int id = p.idx0[d];
      if (tid < 128){
        float h = 0.f;
        #pragma unroll
        for (int j = 0; j < 7; ++j) h += p.x[s*7+j]*p.W0[j*128+tid];
        atomicAdd(&p.acc0[(size_t)id*128 + tid], e*h);
      } else if (tid == 128) atomicAdd(&p.s0[id], e);
    }
  }
  grid.sync();

  // ---- P5: node level-0 finalize + hh0 + av ----
  {
    int n0 = min(p.cnt[3], C0);
    for (int b = bid; b < n0; b += gridDim.x){
      int u = p.list0[b];
      if (tid < 128){
        float res = 0.f;
        #pragma unroll
        for (int j = 0; j < 7; ++j) res += p.x[u*7+j]*p.Wr0[j*128+tid];
        float v = selu_f(p.acc0[(size_t)b*128+tid]/(p.s0[b]+1e-9f) + p.b0[tid] + res);
        p.f0[(size_t)b*128+tid] = v;
        sf[tid] = v;
      }
      __syncthreads();
      float hv = 0.f;
      if (tid < 128){
        for (int j = 0; j < 128; ++j) hv += sf[j]*p.Wf[j*128+tid];
        p.hh0[(size_t)b*128+tid] = hv;
        red[tid] = hv*p.a1f[tid];
      }
      __syncthreads();
      for (int st = 64; st > 0; st >>= 1){ if (tid < st) red[tid] += red[tid+st]; __syncthreads(); }
      if (tid == 0) p.av10[b] = red[0];
      __syncthreads();
      if (tid < 128) red[tid] = hv*p.a2f[tid];
      __syncthreads();
      for (int st = 64; st > 0; st >>= 1){ if (tid < st) red[tid] += red[tid+st]; __syncthreads(); }
      if (tid == 0) p.av20[b] = red[0];
      __syncthreads();
    }
  }
  grid.sync();

  // ---- P6: level-1 edge accumulation ----
  {
    int ne1 = min(p.cnt[1], CE1);
    for (int i = bid; i < ne1; i += gridDim.x){
      int s = p.e1s[i], d = p.e1d[i];
      int i0s = p.idx0[s], i0d = p.idx0[d], i1 = p.idx1[d];
      if (i0s < 0 || i1 < 0) continue;
      float e = expf(lrelu(p.av10[i0s] + p.av20[i0d], 0.2f));
      if (tid < 128) atomicAdd(&p.acc1[(size_t)i1*128 + tid], e*p.hh0[(size_t)i0s*128 + tid]);
      else if (tid == 128) atomicAdd(&p.s1[i1], e);
    }
  }
  grid.sync();

  // ---- P7: node level-1 finalize + hh1 + av ----
  {
    int n1 = min(p.cnt[4], C1);
    for (int b = bid; b < n1; b += gridDim.x){
      int u = p.list1[b];
      int i0 = p.idx0[u];
      if (tid < 128){
        float f0v = p.f0[(size_t)i0*128+tid];
        float lo = selu_f(p.acc1[(size_t)b*128+tid]/(p.s1[b]+1e-9f) + p.bf[tid] + f0v);
        float v = f0v + lo;
        p.f1[(size_t)b*128+tid] = v;
        sf[tid] = v;
      }
      __syncthreads();
      float hv = 0.f;
      if (tid < 128){
        for (int j = 0; j < 128; ++j) hv += sf[j]*p.Wf[16384 + j*128+tid];
        p.hh1[(size_t)b*128+tid] = hv;
        red[tid] = hv*p.a1f[128+tid];
      }
      __syncthreads();
      for (int st = 64; st > 0; st >>= 1){ if (tid < st) red[tid] += red[tid+st]; __syncthreads(); }
      if (tid == 0) p.av11[b] = red[0];
      __syncthreads();
      if (tid < 128) red[tid] = hv*p.a2f[128+tid];
      __syncthreads();
      for (int st = 64; st > 0; st >>= 1){ if (tid < st) red[tid] += red[tid+st]; __syncthreads(); }
      if (tid == 0) p.av21[b] = red[0];
      __syncthreads();
    }
  }
  grid.sync();

  // ---- P8: layer-2 at node t + fc + output (block 0 only) ----
  if (bid == 0){
    int ne2 = min(p.cnt[2], CE2);
    float acc = 0.f, s2 = 0.f;
    for (int i = 0; i < ne2; ++i){
      int i1s = p.idx1[p.e2s[i]];
      if (i1s < 0) continue;
      float e = expf(lrelu(p.av11[i1s] + p.av21[0], 0.2f));
      s2 += e;
      if (tid < 128) acc += e*p.hh1[(size_t)i1s*128 + tid];
    }
    if (tid < 128){
      float f1v = p.f1[tid];                       // slot 0 == node t
      float lo = selu_f(acc/(s2+1e-9f) + p.bf[128+tid] + f1v);
      red[tid] = (f1v + lo)*p.Wfc[tid];
    }
    __syncthreads();
    for (int st = 64; st > 0; st >>= 1){ if (tid < st) red[tid] += red[tid+st]; __syncthreads(); }
    if (tid == 0) p.out[0] = lrelu(red[0] + p.bfc[0], 0.01f);
  }
}

extern "C" void kernel_launch(void* const* d_in, const int* in_sizes, int n_in,
                              void* d_out, int out_size, void* d_ws, size_t ws_size,
                              hipStream_t stream){
  (void)n_in; (void)out_size;
  KP p;
  p.x    = (const float*)d_in[0];
  p.ei   = (const int*)  d_in[1];
  p.W0   = (const float*)d_in[2];
  p.a1_0 = (const float*)d_in[3];
  p.a2_0 = (const float*)d_in[4];
  p.b0   = (const float*)d_in[5];
  p.Wr0  = (const float*)d_in[6];
  // d_in[7..9] (Wa0,ba0,ua0) unused: SimpleAtt over T=1 is identity
  p.Wf   = (const float*)d_in[10];
  p.a1f  = (const float*)d_in[11];
  p.a2f  = (const float*)d_in[12];
  p.bf   = (const float*)d_in[13];
  // d_in[14..16] (Waf,baf,uaf) unused: identity
  p.Wfc  = (const float*)d_in[17];
  p.bfc  = (const float*)d_in[18];
  p.out  = (float*)d_out;

  p.N = in_sizes[0] / 7;
  p.E = in_sizes[1] / 2;
  p.t = p.N - 1;

  char* q = (char*)d_ws;
  auto alloc = [&](size_t bytes) -> void* {
    void* r = (void*)q;
    q += (bytes + 255) & ~(size_t)255;
    return r;
  };
  p.cnt  = (int*)  alloc(64);
  p.wa   = (float*)alloc(sizeof(float)*16);
  p.idx0 = (int*)  alloc(sizeof(int)*(size_t)p.N);
  p.idx1 = (int*)  alloc(sizeof(int)*(size_t)p.N);
  p.list0= (int*)  alloc(sizeof(int)*C0);
  p.list1= (int*)  alloc(sizeof(int)*C1);
  p.s0   = (float*)alloc(sizeof(float)*C0);
  p.acc0 = (float*)alloc(sizeof(float)*(size_t)C0*128);
  p.s1   = (float*)alloc(sizeof(float)*C1);
  p.acc1 = (float*)alloc(sizeof(float)*(size_t)C1*128);
  p.e0s  = (int*)  alloc(sizeof(int)*CE0);
  p.e0d  = (int*)  alloc(sizeof(int)*CE0);
  p.e1s  = (int*)  alloc(sizeof(int)*CE1);
  p.e1d  = (int*)  alloc(sizeof(int)*CE1);
  p.e2s  = (int*)  alloc(sizeof(int)*CE2);
  p.f0   = (float*)alloc(sizeof(float)*(size_t)C0*128);
  p.hh0  = (float*)alloc(sizeof(float)*(size_t)C0*128);
  p.av10 = (float*)alloc(sizeof(float)*C0);
  p.av20 = (float*)alloc(sizeof(float)*C0);
  p.f1   = (float*)alloc(sizeof(float)*(size_t)C1*128);
  p.hh1  = (float*)alloc(sizeof(float)*(size_t)C1*128);
  p.av11 = (float*)alloc(sizeof(float)*C1);
  p.av21 = (float*)alloc(sizeof(float)*C1);
  if ((size_t)(q - (char*)d_ws) > ws_size) return;  // ~17 MB needed

  void* args[] = { &p };
  hipLaunchCooperativeKernel(reinterpret_cast<const void*>(&fused),
                             dim3(NB), dim3(NT), args, 0, stream);
}

// Round 4
// 49.034 us; speedup vs baseline: 3.5765x; 3.5765x over previous
//
#include <hip/hip_runtime.h>
#include <hip/hip_bf16.h>

#define C0   8192
#define C1   2048
#define CE1  32768
#define CE2  2048

struct KP {
  const float* x; const int* ei;
  const float* W0; const float* a1_0; const float* a2_0; const float* b0; const float* Wr0;
  const float* Wf; const float* a1f; const float* a2f; const float* bf;
  const float* Wfc; const float* bfc;
  float* out;
  int N, E, t;
  int* cnt;     // [1]=ne1 [2]=ne2 [3]=n0 [4]=n1
  float* wa;    // wa1[0..6], wa2[8..14]
  int* idx0; int* idx1; int* list0; int* list1;
  float* s0; float* acc0; float* s1; float* acc1;
  int* e1s; int* e1d; int* e2s;
  float* f0; float* hh0; float* av10; float* av20;
  float* f1; float* hh1; float* av11; float* av21;
};

__device__ __forceinline__ float lrelu(float v, float a){ return v >= 0.f ? v : a*v; }
__device__ __forceinline__ float selu_f(float v){
  const float sc = 1.0507009873554805f, al = 1.6732632423543772f;
  return v > 0.f ? sc*v : sc*al*expm1f(v);
}
// claim node into compact set; zero its denom + 128-wide accumulator slot
__device__ __forceinline__ void claim(int* idx, int* list, int* cnt, int cap, int node,
                                      float* s, float* acc){
  if (atomicCAS(&idx[node], -1, -2) == -1){
    int slot = atomicAdd(cnt, 1);
    if (slot < cap){
      list[slot] = node;
      s[slot] = 0.f;
      float4* a = (float4*)(acc + (size_t)slot * 128);
      #pragma unroll
      for (int k = 0; k < 32; ++k) a[k] = make_float4(0.f,0.f,0.f,0.f);
      idx[node] = slot;
    }
  }
}

// K0: idx maps, counters, wa precompute, slot 0 (node t) for both levels
__global__ void k_init(KP p){
  int u = blockIdx.x*blockDim.x + threadIdx.x;
  if (u < p.N){
    int v = (u == p.t) ? 0 : -1;
    p.idx0[u] = v; p.idx1[u] = v;
  }
  if (blockIdx.x == 0){
    int tid = threadIdx.x;
    if (tid < 7){
      float sA = 0.f, sB = 0.f;
      for (int k = 0; k < 128; ++k){ float wv = p.W0[tid*128+k]; sA += wv*p.a1_0[k]; sB += wv*p.a2_0[k]; }
      p.wa[tid] = sA; p.wa[8+tid] = sB;
    }
    if (tid < 128){ p.acc0[tid] = 0.f; p.acc1[tid] = 0.f; }
    else if (tid == 128){
      p.s0[0] = 0.f; p.s1[0] = 0.f; p.list0[0] = p.t; p.list1[0] = p.t;
      p.cnt[1] = 0; p.cnt[2] = 0; p.cnt[3] = 1; p.cnt[4] = 1;
    }
  }
}

// K1: edges into t -> e2 list; claim S1 (and same nodes into S0)
__global__ void k_scan1(KP p){
  int gtid = blockIdx.x*blockDim.x + threadIdx.x;
  int nv = p.E >> 2;
  const int4* d4 = (const int4*)(p.ei + p.E);
  if (gtid < nv){
    int4 dv = d4[gtid];
    #pragma unroll
    for (int m = 0; m < 4; ++m){
      int dd = (&dv.x)[m];
      if (dd == p.t){
        int s = p.ei[4*gtid + m];
        int slot = atomicAdd(&p.cnt[2], 1);
        if (slot < CE2) p.e2s[slot] = s;
        claim(p.idx1, p.list1, &p.cnt[4], C1, s, p.s1, p.acc1);
        claim(p.idx0, p.list0, &p.cnt[3], C0, s, p.s0, p.acc0);
      }
    }
  }
  if (gtid < (p.E & 3)){
    int i = nv*4 + gtid;
    int dd = p.ei[p.E + i];
    if (dd == p.t){
      int s = p.ei[i];
      int slot = atomicAdd(&p.cnt[2], 1);
      if (slot < CE2) p.e2s[slot] = s;
      claim(p.idx1, p.list1, &p.cnt[4], C1, s, p.s1, p.acc1);
      claim(p.idx0, p.list0, &p.cnt[3], C0, s, p.s0, p.acc0);
    }
  }
}

// K2: edges into S1 -> e1 list; claim srcs into S0
__global__ void k_scan2(KP p){
  __shared__ int bm[2048];
  int tid = threadIdx.x;
  int bmw = (p.N + 31) >> 5;
  for (int i = tid; i < bmw; i += blockDim.x) bm[i] = 0;
  __syncthreads();
  int n1 = min(p.cnt[4], C1);
  for (int i = tid; i < n1; i += blockDim.x){ int u = p.list1[i]; atomicOr(&bm[u>>5], 1 << (u&31)); }
  __syncthreads();
  int gtid = blockIdx.x*blockDim.x + tid;
  int nv = p.E >> 2;
  const int4* d4 = (const int4*)(p.ei + p.E);
  if (gtid < nv){
    int4 dv = d4[gtid];
    #pragma unroll
    for (int m = 0; m < 4; ++m){
      int dd = (&dv.x)[m];
      if ((bm[dd>>5] >> (dd&31)) & 1){
        int s = p.ei[4*gtid + m];
        int slot = atomicAdd(&p.cnt[1], 1);
        if (slot < CE1){ p.e1s[slot] = s; p.e1d[slot] = dd; }
        claim(p.idx0, p.list0, &p.cnt[3], C0, s, p.s0, p.acc0);
      }
    }
  }
  if (gtid < (p.E & 3)){
    int i = nv*4 + gtid;
    int dd = p.ei[p.E + i];
    if ((bm[dd>>5] >> (dd&31)) & 1){
      int s = p.ei[i];
      int slot = atomicAdd(&p.cnt[1], 1);
      if (slot < CE1){ p.e1s[slot] = s; p.e1d[slot] = dd; }
      claim(p.idx0, p.list0, &p.cnt[3], C0, s, p.s0, p.acc0);
    }
  }
}

// K3: edges into S0 -> FUSED level-0 aggregation (wave-cooperative, no list)
__global__ void k_scan3(KP p){
  __shared__ int bm[2048];
  int tid = threadIdx.x;
  int bmw = (p.N + 31) >> 5;
  for (int i = tid; i < bmw; i += blockDim.x) bm[i] = 0;
  __syncthreads();
  int n0 = min(p.cnt[3], C0);
  for (int i = tid; i < n0; i += blockDim.x){ int u = p.list0[i]; atomicOr(&bm[u>>5], 1 << (u&31)); }
  __syncthreads();
  int gtid = blockIdx.x*blockDim.x + tid;
  int lane = tid & 63;
  int nv = p.E >> 2;
  const int4* d4 = (const int4*)(p.ei + p.E);
  bool inb = gtid < nv;
  int4 dv = make_int4(-1,-1,-1,-1);
  if (inb) dv = d4[gtid];
  #pragma unroll
  for (int m = 0; m < 4; ++m){
    int dd = inb ? (&dv.x)[m] : -1;
    bool match = (dd >= 0) && ((bm[dd>>5] >> (dd&31)) & 1);
    int sv = 0;
    if (match) sv = p.ei[4*gtid + m];
    unsigned long long b = __ballot(match);
    while (b){
      int l = __ffsll((long long)b) - 1; b &= b - 1;
      int s = __shfl(sv, l), d = __shfl(dd, l);
      float f = 0.f;
      #pragma unroll
      for (int j = 0; j < 7; ++j) f += p.x[s*7+j]*p.wa[j] + p.x[d*7+j]*p.wa[8+j];
      float e = expf(lrelu(f, 0.2f));
      int id = p.idx0[d];
      if (id >= 0){
        float h0 = 0.f, h1 = 0.f;
        #pragma unroll
        for (int j = 0; j < 7; ++j){
          float xs = p.x[s*7+j];
          float2 w2 = *(const float2*)&p.W0[j*128 + 2*lane];
          h0 += xs*w2.x; h1 += xs*w2.y;
        }
        atomicAdd(&p.acc0[(size_t)id*128 + 2*lane    ], e*h0);
        atomicAdd(&p.acc0[(size_t)id*128 + 2*lane + 1], e*h1);
        if (lane == 0) atomicAdd(&p.s0[id], e);
      }
    }
  }
  // scalar tail (runs only if E%4 != 0; E=600000 -> never)
  if (gtid < (p.E & 3)){
    int i = nv*4 + gtid;
    int dd = p.ei[p.E + i];
    if ((bm[dd>>5] >> (dd&31)) & 1){
      int s = p.ei[i];
      float f = 0.f;
      for (int j = 0; j < 7; ++j) f += p.x[s*7+j]*p.wa[j] + p.x[dd*7+j]*p.wa[8+j];
      float e = expf(lrelu(f, 0.2f));
      int id = p.idx0[dd];
      if (id >= 0){
        for (int k = 0; k < 128; ++k){
          float h = 0.f;
          for (int j = 0; j < 7; ++j) h += p.x[s*7+j]*p.W0[j*128+k];
          atomicAdd(&p.acc0[(size_t)id*128 + k], e*h);
        }
        atomicAdd(&p.s0[id], e);
      }
    }
  }
}

// K4: level-0 finalize + hh0 + av reductions (block=128, one node per block)
__global__ void __launch_bounds__(128) k_fin0(KP p){
  __shared__ float sf[128];
  __shared__ float2 red[128];
  int tid = threadIdx.x;
  int n0 = min(p.cnt[3], C0);
  for (int b = blockIdx.x; b < n0; b += gridDim.x){
    int u = p.list0[b];
    float res = 0.f;
    #pragma unroll
    for (int j = 0; j < 7; ++j) res += p.x[u*7+j]*p.Wr0[j*128+tid];
    float v = selu_f(p.acc0[(size_t)b*128+tid]/(p.s0[b]+1e-9f) + p.b0[tid] + res);
    p.f0[(size_t)b*128+tid] = v;
    sf[tid] = v;
    __syncthreads();
    float hv = 0.f;
    #pragma unroll 8
    for (int j = 0; j < 128; ++j) hv += sf[j]*p.Wf[j*128+tid];
    p.hh0[(size_t)b*128+tid] = hv;
    red[tid] = make_float2(hv*p.a1f[tid], hv*p.a2f[tid]);
    __syncthreads();
    for (int st = 64; st > 0; st >>= 1){
      if (tid < st){ red[tid].x += red[tid+st].x; red[tid].y += red[tid+st].y; }
      __syncthreads();
    }
    if (tid == 0){ p.av10[b] = red[0].x; p.av20[b] = red[0].y; }
    __syncthreads();
  }
}

// K5: level-1 edge aggregation, wave-per-edge
__global__ void k_agg1(KP p){
  int gtid = blockIdx.x*blockDim.x + threadIdx.x;
  int wv = gtid >> 6, lane = gtid & 63;
  int nw = (gridDim.x*blockDim.x) >> 6;
  int ne1 = min(p.cnt[1], CE1);
  for (int i = wv; i < ne1; i += nw){
    int s = p.e1s[i], d = p.e1d[i];
    int i0s = p.idx0[s], i0d = p.idx0[d], i1 = p.idx1[d];
    if (i0s < 0 || i1 < 0) continue;
    float e = expf(lrelu(p.av10[i0s] + p.av20[i0d], 0.2f));
    float2 hv = *(const float2*)&p.hh0[(size_t)i0s*128 + 2*lane];
    atomicAdd(&p.acc1[(size_t)i1*128 + 2*lane    ], e*hv.x);
    atomicAdd(&p.acc1[(size_t)i1*128 + 2*lane + 1], e*hv.y);
    if (lane == 0) atomicAdd(&p.s1[i1], e);
  }
}

// K6: level-1 finalize + hh1 + av reductions
__global__ void __launch_bounds__(128) k_fin1(KP p){
  __shared__ float sf[128];
  __shared__ float2 red[128];
  int tid = threadIdx.x;
  int n1 = min(p.cnt[4], C1);
  for (int b = blockIdx.x; b < n1; b += gridDim.x){
    int u = p.list1[b];
    int i0 = p.idx0[u];
    float f0v = (i0 >= 0) ? p.f0[(size_t)i0*128+tid] : 0.f;
    float lo = selu_f(p.acc1[(size_t)b*128+tid]/(p.s1[b]+1e-9f) + p.bf[tid] + f0v);
    float v = f0v + lo;
    p.f1[(size_t)b*128+tid] = v;
    sf[tid] = v;
    __syncthreads();
    float hv = 0.f;
    #pragma unroll 8
    for (int j = 0; j < 128; ++j) hv += sf[j]*p.Wf[16384 + j*128+tid];
    p.hh1[(size_t)b*128+tid] = hv;
    red[tid] = make_float2(hv*p.a1f[128+tid], hv*p.a2f[128+tid]);
    __syncthreads();
    for (int st = 64; st > 0; st >>= 1){
      if (tid < st){ red[tid].x += red[tid+st].x; red[tid].y += red[tid+st].y; }
      __syncthreads();
    }
    if (tid == 0){ p.av11[b] = red[0].x; p.av21[b] = red[0].y; }
    __syncthreads();
  }
}

// K7: layer-2 at t + fc + output (parallelized edge loop)
__global__ void __launch_bounds__(128) k_l2(KP p){
  __shared__ float se[128];
  __shared__ int   si[128];
  __shared__ float red[128];
  int tid = threadIdx.x;
  int ne2 = min(p.cnt[2], CE2);
  float acc = 0.f, s2 = 0.f;
  for (int base = 0; base < ne2; base += 128){
    int i = base + tid;
    float e = 0.f; int ii = -1;
    if (i < ne2){
      ii = p.idx1[p.e2s[i]];
      if (ii >= 0) e = expf(lrelu(p.av11[ii] + p.av21[0], 0.2f));
    }
    se[tid] = e; si[tid] = ii;
    __syncthreads();
    int c = min(128, ne2 - base);
    for (int q = 0; q < c; ++q){
      if (si[q] >= 0){
        s2  += se[q];
        acc += se[q]*p.hh1[(size_t)si[q]*128 + tid];
      }
    }
    __syncthreads();
  }
  float f1v = p.f1[tid];                       // slot 0 == node t
  float lo = selu_f(acc/(s2+1e-9f) + p.bf[128+tid] + f1v);
  red[tid] = (f1v + lo)*p.Wfc[tid];
  __syncthreads();
  for (int st = 64; st > 0; st >>= 1){ if (tid < st) red[tid] += red[tid+st]; __syncthreads(); }
  if (tid == 0) p.out[0] = lrelu(red[0] + p.bfc[0], 0.01f);
}

extern "C" void kernel_launch(void* const* d_in, const int* in_sizes, int n_in,
                              void* d_out, int out_size, void* d_ws, size_t ws_size,
                              hipStream_t stream){
  (void)n_in; (void)out_size;
  KP p;
  p.x    = (const float*)d_in[0];
  p.ei   = (const int*)  d_in[1];
  p.W0   = (const float*)d_in[2];
  p.a1_0 = (const float*)d_in[3];
  p.a2_0 = (const float*)d_in[4];
  p.b0   = (const float*)d_in[5];
  p.Wr0  = (const float*)d_in[6];
  // d_in[7..9] (Wa0,ba0,ua0) unused: SimpleAtt over T=1 is identity
  p.Wf   = (const float*)d_in[10];
  p.a1f  = (const float*)d_in[11];
  p.a2f  = (const float*)d_in[12];
  p.bf   = (const float*)d_in[13];
  // d_in[14..16] (Waf,baf,uaf) unused: identity
  p.Wfc  = (const float*)d_in[17];
  p.bfc  = (const float*)d_in[18];
  p.out  = (float*)d_out;

  p.N = in_sizes[0] / 7;
  p.E = in_sizes[1] / 2;
  p.t = p.N - 1;

  char* q = (char*)d_ws;
  auto alloc = [&](size_t bytes) -> void* {
    void* r = (void*)q;
    q += (bytes + 255) & ~(size_t)255;
    return r;
  };
  p.cnt  = (int*)  alloc(64);
  p.wa   = (float*)alloc(sizeof(float)*16);
  p.idx0 = (int*)  alloc(sizeof(int)*(size_t)p.N);
  p.idx1 = (int*)  alloc(sizeof(int)*(size_t)p.N);
  p.list0= (int*)  alloc(sizeof(int)*C0);
  p.list1= (int*)  alloc(sizeof(int)*C1);
  p.s0   = (float*)alloc(sizeof(float)*C0);
  p.acc0 = (float*)alloc(sizeof(float)*(size_t)C0*128);
  p.s1   = (float*)alloc(sizeof(float)*C1);
  p.acc1 = (float*)alloc(sizeof(float)*(size_t)C1*128);
  p.e1s  = (int*)  alloc(sizeof(int)*CE1);
  p.e1d  = (int*)  alloc(sizeof(int)*CE1);
  p.e2s  = (int*)  alloc(sizeof(int)*CE2);
  p.f0   = (float*)alloc(sizeof(float)*(size_t)C0*128);
  p.hh0  = (float*)alloc(sizeof(float)*(size_t)C0*128);
  p.av10 = (float*)alloc(sizeof(float)*C0);
  p.av20 = (float*)alloc(sizeof(float)*C0);
  p.f1   = (float*)alloc(sizeof(float)*(size_t)C1*128);
  p.hh1  = (float*)alloc(sizeof(float)*(size_t)C1*128);
  p.av11 = (float*)alloc(sizeof(float)*C1);
  p.av21 = (float*)alloc(sizeof(float)*C1);
  if ((size_t)(q - (char*)d_ws) > ws_size) return;  // ~16 MB needed

  int nb  = (p.N + 255) / 256;
  int eb4 = ((p.E >> 2) + 255) / 256;
  k_init <<<nb , 256, 0, stream>>>(p);
  k_scan1<<<eb4, 256, 0, stream>>>(p);
  k_scan2<<<eb4, 256, 0, stream>>>(p);
  k_scan3<<<eb4, 256, 0, stream>>>(p);
  k_fin0 <<<256, 128, 0, stream>>>(p);
  k_agg1 <<<64 , 256, 0, stream>>>(p);
  k_fin1 <<<32 , 128, 0, stream>>>(p);
  k_l2   <<<1  , 128, 0, stream>>>(p);
}